// Round 1
// baseline (802.822 us; speedup 1.0000x reference)
//
#include <hip/hip_runtime.h>
#include <math.h>

#define BATCH 65536
#define DIM 128
#define NEG_K 5

__device__ __forceinline__ float wave_reduce_sum(float v) {
    #pragma unroll
    for (int off = 32; off > 0; off >>= 1)
        v += __shfl_xor(v, off, 64);
    return v;
}

__device__ __forceinline__ float log_sigmoid(float x) {
    // numerically stable: min(x,0) - log1p(exp(-|x|))
    return fminf(x, 0.0f) - log1pf(__expf(-fabsf(x)));
}

__global__ void sg_zero(float* ws) {
    if (threadIdx.x == 0 && blockIdx.x == 0) ws[0] = 0.0f;
}

__global__ __launch_bounds__(256) void sg_loss(
    const int* __restrict__ center, const int* __restrict__ context,
    const int* __restrict__ negs, const float* __restrict__ u_w,
    const float* __restrict__ v_w, float* __restrict__ ws)
{
    const int lane = threadIdx.x & 63;
    const int wib  = threadIdx.x >> 6;             // wave in block (0..3)
    const int wave_id   = blockIdx.x * (blockDim.x >> 6) + wib;
    const int num_waves = gridDim.x * (blockDim.x >> 6);

    float local = 0.0f;
    for (int b = wave_id; b < BATCH; b += num_waves) {
        const size_t c_row = (size_t)center[b]  * DIM;
        const size_t t_row = (size_t)context[b] * DIM;
        const float2 c = ((const float2*)(u_w + c_row))[lane];
        const float2 t = ((const float2*)(v_w + t_row))[lane];

        float pp = c.x * t.x + c.y * t.y;
        float pn[NEG_K];
        #pragma unroll
        for (int k = 0; k < NEG_K; ++k) {
            const size_t n_row = (size_t)negs[b * NEG_K + k] * DIM;
            const float2 nv = ((const float2*)(v_w + n_row))[lane];
            pn[k] = c.x * nv.x + c.y * nv.y;
        }

        float acc = log_sigmoid(wave_reduce_sum(pp));
        #pragma unroll
        for (int k = 0; k < NEG_K; ++k)
            acc += log_sigmoid(-wave_reduce_sum(pn[k]));

        local -= acc;   // loss contribution is -(pos_loss + neg_loss)
    }

    __shared__ float sdata[4];
    if (lane == 0) sdata[wib] = local;   // butterfly leaves full sum in all lanes
    __syncthreads();
    if (threadIdx.x == 0) {
        float s = sdata[0] + sdata[1] + sdata[2] + sdata[3];
        atomicAdd(ws, s);
    }
}

__global__ void sg_finalize(const float* ws, float* out) {
    if (threadIdx.x == 0 && blockIdx.x == 0)
        out[0] = ws[0] / (float)BATCH;
}

extern "C" void kernel_launch(void* const* d_in, const int* in_sizes, int n_in,
                              void* d_out, int out_size, void* d_ws, size_t ws_size,
                              hipStream_t stream) {
    const int*   center  = (const int*)  d_in[0];
    const int*   context = (const int*)  d_in[1];
    const int*   negs    = (const int*)  d_in[2];
    const float* u_w     = (const float*)d_in[3];
    const float* v_w     = (const float*)d_in[4];
    float* out = (float*)d_out;
    float* ws  = (float*)d_ws;

    sg_zero<<<1, 64, 0, stream>>>(ws);
    // 2048 blocks * 4 waves = 8192 waves -> one full-occupancy pass,
    // 8 batch elements per wave.
    sg_loss<<<2048, 256, 0, stream>>>(center, context, negs, u_w, v_w, ws);
    sg_finalize<<<1, 64, 0, stream>>>(ws, out);
}

// Round 2
// 796.935 us; speedup vs baseline: 1.0074x; 1.0074x over previous
//
#include <hip/hip_runtime.h>
#include <math.h>

#define BATCH 65536
#define DIM 128
#define NEG_K 5
#define NWAVES 8192          // 2048 blocks * 4 waves
#define PAIRS  (BATCH / 2)   // 32768 element-pairs, 4 per wave

// Reduce within each 32-lane half of the wave64 (offsets 16..1 stay in-half).
__device__ __forceinline__ float half_reduce(float v) {
    #pragma unroll
    for (int off = 16; off > 0; off >>= 1)
        v += __shfl_xor(v, off, 64);
    return v;
}

__device__ __forceinline__ float full_reduce(float v) {
    #pragma unroll
    for (int off = 32; off > 0; off >>= 1)
        v += __shfl_xor(v, off, 64);
    return v;
}

__device__ __forceinline__ float log_sigmoid(float x) {
    // numerically stable: min(x,0) - log1p(exp(-|x|))
    return fminf(x, 0.0f) - log1pf(__expf(-fabsf(x)));
}

__global__ void sg_zero(float* out) {
    if (threadIdx.x == 0 && blockIdx.x == 0) out[0] = 0.0f;
}

__global__ __launch_bounds__(256) void sg_loss(
    const int* __restrict__ center, const int* __restrict__ context,
    const int* __restrict__ negs, const float* __restrict__ u_w,
    const float* __restrict__ v_w, float* __restrict__ out)
{
    const int tid  = threadIdx.x;
    const int lane = tid & 63;
    const int half = lane >> 5;        // 0 or 1: which element of the pair
    const int sl   = lane & 31;        // sub-lane within the 32-lane group
    const int wib  = tid >> 6;
    const int wave_id = blockIdx.x * (blockDim.x >> 6) + wib;

    float local = 0.0f;
    #pragma unroll 2
    for (int it = 0; it < PAIRS / NWAVES; ++it) {
        const int b = 2 * (wave_id + it * NWAVES) + half;

        const size_t c_row = (size_t)center[b]  * DIM;
        const size_t t_row = (size_t)context[b] * DIM;
        const float4 c = ((const float4*)(u_w + c_row))[sl];
        const float4 t = ((const float4*)(v_w + t_row))[sl];

        float pp = c.x * t.x + c.y * t.y + c.z * t.z + c.w * t.w;
        float pn[NEG_K];
        #pragma unroll
        for (int k = 0; k < NEG_K; ++k) {
            const size_t n_row = (size_t)negs[b * NEG_K + k] * DIM;
            const float4 nv = ((const float4*)(v_w + n_row))[sl];
            pn[k] = c.x * nv.x + c.y * nv.y + c.z * nv.z + c.w * nv.w;
        }

        float acc = log_sigmoid(half_reduce(pp));
        #pragma unroll
        for (int k = 0; k < NEG_K; ++k)
            acc += log_sigmoid(-half_reduce(pn[k]));

        local -= acc;   // all 32 lanes of this half hold the identical value
    }

    // Each element's contribution is replicated on 32 lanes -> scale by 1/32
    // (exact), then one 64-lane butterfly gives the wave total on all lanes.
    float wsum = full_reduce(local * (1.0f / 32.0f));

    __shared__ float sdata[4];
    if (lane == 0) sdata[wib] = wsum;
    __syncthreads();
    if (tid == 0) {
        float s = sdata[0] + sdata[1] + sdata[2] + sdata[3];
        atomicAdd(out, s * (1.0f / (float)BATCH));  // pre-scaled mean
    }
}

extern "C" void kernel_launch(void* const* d_in, const int* in_sizes, int n_in,
                              void* d_out, int out_size, void* d_ws, size_t ws_size,
                              hipStream_t stream) {
    const int*   center  = (const int*)  d_in[0];
    const int*   context = (const int*)  d_in[1];
    const int*   negs    = (const int*)  d_in[2];
    const float* u_w     = (const float*)d_in[3];
    const float* v_w     = (const float*)d_in[4];
    float* out = (float*)d_out;

    sg_zero<<<1, 64, 0, stream>>>(out);
    sg_loss<<<2048, 256, 0, stream>>>(center, context, negs, u_w, v_w, out);
}

// Round 3
// 795.088 us; speedup vs baseline: 1.0097x; 1.0023x over previous
//
#include <hip/hip_runtime.h>
#include <math.h>

#define BATCH 65536
#define DIM 128
#define NEG_K 5
#define BLOCKS 2048
#define TPB 256
#define NWAVES (BLOCKS * (TPB / 64))   // 8192
#define PAIRS  (BATCH / 2)             // 32768 element-pairs, 4 per wave

// Reduce within each 32-lane half of the wave64 (offsets 16..1 stay in-half).
__device__ __forceinline__ float half_reduce(float v) {
    #pragma unroll
    for (int off = 16; off > 0; off >>= 1)
        v += __shfl_xor(v, off, 64);
    return v;
}

__device__ __forceinline__ float full_reduce(float v) {
    #pragma unroll
    for (int off = 32; off > 0; off >>= 1)
        v += __shfl_xor(v, off, 64);
    return v;
}

__device__ __forceinline__ float log_sigmoid(float x) {
    // numerically stable: min(x,0) - log1p(exp(-|x|))
    return fminf(x, 0.0f) - log1pf(__expf(-fabsf(x)));
}

__global__ __launch_bounds__(TPB) void sg_loss(
    const int* __restrict__ center, const int* __restrict__ context,
    const int* __restrict__ negs, const float* __restrict__ u_w,
    const float* __restrict__ v_w, float* __restrict__ partials)
{
    const int tid  = threadIdx.x;
    const int lane = tid & 63;
    const int half = lane >> 5;        // 0 or 1: which element of the pair
    const int sl   = lane & 31;        // sub-lane within the 32-lane group
    const int wib  = tid >> 6;
    const int wave_id = blockIdx.x * (TPB >> 6) + wib;

    float local = 0.0f;
    #pragma unroll 2
    for (int it = 0; it < PAIRS / NWAVES; ++it) {
        const int b = 2 * (wave_id + it * NWAVES) + half;

        const size_t c_row = (size_t)center[b]  * DIM;
        const size_t t_row = (size_t)context[b] * DIM;
        const float4 c = ((const float4*)(u_w + c_row))[sl];
        const float4 t = ((const float4*)(v_w + t_row))[sl];

        float pp = c.x * t.x + c.y * t.y + c.z * t.z + c.w * t.w;
        float pn[NEG_K];
        #pragma unroll
        for (int k = 0; k < NEG_K; ++k) {
            const size_t n_row = (size_t)negs[b * NEG_K + k] * DIM;
            const float4 nv = ((const float4*)(v_w + n_row))[sl];
            pn[k] = c.x * nv.x + c.y * nv.y + c.z * nv.z + c.w * nv.w;
        }

        float acc = log_sigmoid(half_reduce(pp));
        #pragma unroll
        for (int k = 0; k < NEG_K; ++k)
            acc += log_sigmoid(-half_reduce(pn[k]));

        local -= acc;   // all 32 lanes of this half hold the identical value
    }

    // Each element's contribution is replicated on 32 lanes -> scale by 1/32
    // (exact), then one 64-lane butterfly gives the wave total on all lanes.
    float wsum = full_reduce(local * (1.0f / 32.0f));

    __shared__ float sdata[TPB / 64];
    if (lane == 0) sdata[wib] = wsum;
    __syncthreads();
    if (tid == 0) {
        // Contention-free: one plain store per block, no atomics.
        partials[blockIdx.x] = sdata[0] + sdata[1] + sdata[2] + sdata[3];
    }
}

__global__ __launch_bounds__(256) void sg_reduce(const float* __restrict__ partials,
                                                 float* __restrict__ out)
{
    const int tid = threadIdx.x;
    float s = 0.0f;
    #pragma unroll
    for (int i = 0; i < BLOCKS / 256; ++i)      // 8 per thread
        s += partials[tid + i * 256];
    s = full_reduce(s);

    __shared__ float sdata[4];
    const int lane = tid & 63, wib = tid >> 6;
    if (lane == 0) sdata[wib] = s;
    __syncthreads();
    if (tid == 0)
        out[0] = (sdata[0] + sdata[1] + sdata[2] + sdata[3]) * (1.0f / (float)BATCH);
}

extern "C" void kernel_launch(void* const* d_in, const int* in_sizes, int n_in,
                              void* d_out, int out_size, void* d_ws, size_t ws_size,
                              hipStream_t stream) {
    const int*   center  = (const int*)  d_in[0];
    const int*   context = (const int*)  d_in[1];
    const int*   negs    = (const int*)  d_in[2];
    const float* u_w     = (const float*)d_in[3];
    const float* v_w     = (const float*)d_in[4];
    float* out      = (float*)d_out;
    float* partials = (float*)d_ws;     // 2048 floats, all overwritten by sg_loss

    sg_loss<<<BLOCKS, TPB, 0, stream>>>(center, context, negs, u_w, v_w, partials);
    sg_reduce<<<1, 256, 0, stream>>>(partials, out);
}